// Round 2
// baseline (171.889 us; speedup 1.0000x reference)
//
#include <hip/hip_runtime.h>
#include <stdint.h>
#include <math.h>

// Multiresolution hash encoding, 16 levels.
// numpy float32 b = exp((log256-log4)/15) lands BELOW 2^0.4 (empirically,
// round-0 A/B test), so grids at i=5,10,15 are 15,63,255 (not 16,64,256):
//   grids = {4,5,6,9,12,15,21,27,36,48,63,84,111,147,194,255}
// kh = 256//grid, P = floor(256/kh)  (reduce_window VALID output size)

#define NLVL 16
#define NB   16

__constant__ int   c_P[NLVL]     = {4,5,6,9,12,15,21,28,36,51,64,85,128,256,256,256};
__constant__ int   c_KH[NLVL]    = {64,51,42,28,21,17,12,9,7,5,4,3,2,1,1,1};
__constant__ float c_G[NLVL]     = {4.f,5.f,6.f,9.f,12.f,15.f,21.f,27.f,36.f,48.f,63.f,84.f,111.f,147.f,194.f,255.f};
// cumulative cells per batch (P^2 prefix sums), c_CUM[16] = total = 229962
__constant__ int   c_CUM[NLVL+1] = {0,16,41,77,158,302,527,968,1752,3048,5649,9745,16970,33354,98890,164426,229962};

#define A_LVLS   8        // levels 0..7: wave-per-cell (kh >= 9)
#define A_CELLS  1752     // cells/batch in levels 0..7
#define B_FIRST  8
#define B_CELLS  228210   // cells/batch in levels 8..15 (229962-1752)

__device__ __forceinline__ uint32_t hash3(float m0, float m1, float m2, float g) {
    uint32_t v0 = (uint32_t)(int)(m0 * g);
    uint32_t v1 = (uint32_t)(int)(m1 * g);
    uint32_t v2 = (uint32_t)(int)(m2 * g);
    return (v0 ^ (v1 * 2654435761u) ^ (v2 * 805459861u)) & 0xFFFFu;
}

// ---- Phase 1a: big windows, one wave per pooled cell, lane-per-column ----
__global__ __launch_bounds__(256) void pool_wave(const float* __restrict__ img,
                                                 uint16_t* __restrict__ gws)
{
    int wid  = blockIdx.x * 4 + (threadIdx.x >> 6);   // grid sized exactly
    int lane = threadIdx.x & 63;
    int b = wid / A_CELLS;
    int r = wid - b * A_CELLS;
    int lvl = 0;
#pragma unroll
    for (int l = 1; l < A_LVLS; ++l) lvl += (r >= c_CUM[l]);
    int P = c_P[lvl], kh = c_KH[lvl];
    int cell = r - c_CUM[lvl];
    int iy = cell / P, ix = cell - iy * P;

    float m0 = -INFINITY, m1 = -INFINITY, m2 = -INFINITY;
    if (lane < kh) {
        const float* p = img + (size_t)b * 196608 + (size_t)(iy * kh) * 256 + ix * kh + lane;
        for (int rr = 0; rr < kh; ++rr) {
            int o = rr * 256;
            m0 = fmaxf(m0, p[o]);
            m1 = fmaxf(m1, p[65536 + o]);
            m2 = fmaxf(m2, p[131072 + o]);
        }
    }
#pragma unroll
    for (int off = 32; off > 0; off >>= 1) {
        m0 = fmaxf(m0, __shfl_xor(m0, off, 64));
        m1 = fmaxf(m1, __shfl_xor(m1, off, 64));
        m2 = fmaxf(m2, __shfl_xor(m2, off, 64));
    }
    if (lane == 0) {
        uint32_t gg = hash3(m0, m1, m2, c_G[lvl]);
        gws[(size_t)c_CUM[lvl] * NB + (size_t)b * (P * P) + cell] = (uint16_t)gg;
    }
}

// ---- Phase 1b: small windows (kh <= 7), one thread per pooled cell ----
__global__ __launch_bounds__(256) void pool_thread(const float* __restrict__ img,
                                                   uint16_t* __restrict__ gws)
{
    int tid = blockIdx.x * 256 + threadIdx.x;
    if (tid >= B_CELLS * NB) return;
    int b = tid / B_CELLS;
    int r = tid - b * B_CELLS + A_CELLS;
    int lvl = B_FIRST;
#pragma unroll
    for (int l = B_FIRST + 1; l < NLVL; ++l) lvl += (r >= c_CUM[l]);
    int P = c_P[lvl], kh = c_KH[lvl];
    int cell = r - c_CUM[lvl];
    int iy = cell / P, ix = cell - iy * P;

    const float* p = img + (size_t)b * 196608 + (size_t)(iy * kh) * 256 + ix * kh;
    float m0 = -INFINITY, m1 = -INFINITY, m2 = -INFINITY;
    for (int rr = 0; rr < kh; ++rr)
        for (int cc = 0; cc < kh; ++cc) {
            int o = rr * 256 + cc;
            m0 = fmaxf(m0, p[o]);
            m1 = fmaxf(m1, p[65536 + o]);
            m2 = fmaxf(m2, p[131072 + o]);
        }
    uint32_t gg = hash3(m0, m1, m2, c_G[lvl]);
    gws[(size_t)c_CUM[lvl] * NB + (size_t)b * (P * P) + cell] = (uint16_t)gg;
}

// ---- Phase 2: gather + bilinear upsample to 256x256, write output ----
// src = (o+0.5)*P/256 - 0.5 = ((2o+1)*P - 256)/512 : exact in int; frac exact in fp32.
__global__ __launch_bounds__(256) void upsample(const float* __restrict__ tab,
                                                const uint16_t* __restrict__ gws,
                                                float* __restrict__ out)
{
    int y     = blockIdx.x;
    int plane = blockIdx.y;          // lvl*16 + b
    int lvl   = plane >> 4;
    int b     = plane & 15;
    int P     = c_P[lvl];
    int x     = threadIdx.x;

    int numy = (2 * y + 1) * P - 256;
    int iy0  = numy >> 9;
    float fy = (float)(numy & 511) * (1.0f / 512.0f);
    int iy1;
    if (iy0 < 0)            { iy0 = 0;     iy1 = 0;     fy = 0.f; }
    else if (iy0 >= P - 1)  { iy0 = P - 1; iy1 = P - 1; fy = 0.f; }
    else                    { iy1 = iy0 + 1; }

    int numx = (2 * x + 1) * P - 256;
    int ix0  = numx >> 9;
    float fx = (float)(numx & 511) * (1.0f / 512.0f);
    int ix1;
    if (ix0 < 0)            { ix0 = 0;     ix1 = 0;     fx = 0.f; }
    else if (ix0 >= P - 1)  { ix0 = P - 1; ix1 = P - 1; fx = 0.f; }
    else                    { ix1 = ix0 + 1; }

    const uint16_t* gb = gws + (size_t)c_CUM[lvl] * NB + (size_t)b * P * P;
    int g00 = gb[iy0 * P + ix0];
    int g01 = gb[iy0 * P + ix1];
    int g10 = gb[iy1 * P + ix0];
    int g11 = gb[iy1 * P + ix1];

    const float* T = tab + (size_t)lvl * 65536 * 3;
    float wx0 = 1.f - fx, wx1 = fx, wy0 = 1.f - fy, wy1 = fy;

    float* o = out + ((size_t)b * 48 + 3 * lvl) * 65536 + (size_t)y * 256 + x;
#pragma unroll
    for (int c = 0; c < 3; ++c) {
        float t00 = T[g00 * 3 + c], t01 = T[g01 * 3 + c];
        float t10 = T[g10 * 3 + c], t11 = T[g11 * 3 + c];
        float v = wy0 * (wx0 * t00 + wx1 * t01) + wy1 * (wx0 * t10 + wx1 * t11);
        o[(size_t)c * 65536] = v;
    }
}

extern "C" void kernel_launch(void* const* d_in, const int* in_sizes, int n_in,
                              void* d_out, int out_size, void* d_ws, size_t ws_size,
                              hipStream_t stream)
{
    const float* img = (const float*)d_in[0];   // (16,3,256,256) f32
    const float* tab = (const float*)d_in[1];   // (16,65536,3) f32
    float* out = (float*)d_out;                 // (16,48,256,256) f32
    uint16_t* gws = (uint16_t*)d_ws;            // 229962*16 uint16 = 7.36 MB

    hipLaunchKernelGGL(pool_wave,   dim3((A_CELLS * NB) / 4), dim3(256), 0, stream, img, gws);
    hipLaunchKernelGGL(pool_thread, dim3((B_CELLS * NB + 255) / 256), dim3(256), 0, stream, img, gws);
    hipLaunchKernelGGL(upsample,    dim3(256, 256), dim3(256), 0, stream, tab, gws, out);
}

// Round 3
// 126.287 us; speedup vs baseline: 1.3611x; 1.3611x over previous
//
#include <hip/hip_runtime.h>
#include <stdint.h>
#include <math.h>

// Multiresolution hash encoding, 16 levels.
// grids = {4,5,6,9,12,15,21,27,36,48,63,84,111,147,194,255}
// kh = 256//grid, P = floor(256/kh).
// Levels 13..15 have kh=1, P=256 -> bilinear is identity -> direct gather.
// Levels 0..12: pool kernels gather T[g] per CELL into dense f_ws (float3),
// upsample reads dense rows via LDS (no scattered gathers).

#define NLVL 16
#define NB   16

__constant__ int   c_P[NLVL]     = {4,5,6,9,12,15,21,28,36,51,64,85,128,256,256,256};
__constant__ int   c_KH[NLVL]    = {64,51,42,28,21,17,12,9,7,5,4,3,2,1,1,1};
__constant__ float c_G[NLVL]     = {4.f,5.f,6.f,9.f,12.f,15.f,21.f,27.f,36.f,48.f,63.f,84.f,111.f,147.f,194.f,255.f};
// prefix sums of P^2 for levels 0..12 (cells per batch), total 33354
__constant__ int   c_CUM[14]     = {0,16,41,77,158,302,527,968,1752,3048,5649,9745,16970,33354};

#define A_LVLS   9        // levels 0..8: wave-per-cell (kh >= 7)
#define A_CELLS  3048     // cells/batch, levels 0..8
#define B2_FIRST 9        // levels 9..12: thread-per-cell (kh <= 5)
#define B2_CELLS 30306    // 33354 - 3048
#define WS_CELLS 33354    // cells/batch, levels 0..12

__device__ __forceinline__ uint32_t hash3(float m0, float m1, float m2, float g) {
    uint32_t v0 = (uint32_t)(int)(m0 * g);
    uint32_t v1 = (uint32_t)(int)(m1 * g);
    uint32_t v2 = (uint32_t)(int)(m2 * g);
    return (v0 ^ (v1 * 2654435761u) ^ (v2 * 805459861u)) & 0xFFFFu;
}

// ---- Phase 1a: levels 0..8, one wave per cell, lane-per-column ----
__global__ __launch_bounds__(256) void pool_wave(const float* __restrict__ img,
                                                 const float* __restrict__ tab,
                                                 float* __restrict__ fws)
{
    int wid  = blockIdx.x * 4 + (threadIdx.x >> 6);
    int lane = threadIdx.x & 63;
    int b = wid / A_CELLS;
    int r = wid - b * A_CELLS;
    int lvl = 0;
#pragma unroll
    for (int l = 1; l < A_LVLS; ++l) lvl += (r >= c_CUM[l]);
    int P = c_P[lvl], kh = c_KH[lvl];
    int cell = r - c_CUM[lvl];
    int iy = cell / P, ix = cell - iy * P;

    float m0 = -INFINITY, m1 = -INFINITY, m2 = -INFINITY;
    if (lane < kh) {
        const float* p = img + (size_t)b * 196608 + (size_t)(iy * kh) * 256 + ix * kh + lane;
        for (int rr = 0; rr < kh; ++rr) {
            int o = rr * 256;
            m0 = fmaxf(m0, p[o]);
            m1 = fmaxf(m1, p[65536 + o]);
            m2 = fmaxf(m2, p[131072 + o]);
        }
    }
#pragma unroll
    for (int off = 32; off > 0; off >>= 1) {
        m0 = fmaxf(m0, __shfl_xor(m0, off, 64));
        m1 = fmaxf(m1, __shfl_xor(m1, off, 64));
        m2 = fmaxf(m2, __shfl_xor(m2, off, 64));
    }
    if (lane == 0) {
        uint32_t gg = hash3(m0, m1, m2, c_G[lvl]);
        const float* T = tab + (size_t)lvl * 196608 + gg * 3;
        float* f = fws + ((size_t)c_CUM[lvl] * NB + (size_t)b * (P * P) + cell) * 3;
        f[0] = T[0]; f[1] = T[1]; f[2] = T[2];
    }
}

// ---- Phase 1b: levels 9..12 (kh <= 5), one thread per cell ----
__global__ __launch_bounds__(256) void pool_thread(const float* __restrict__ img,
                                                   const float* __restrict__ tab,
                                                   float* __restrict__ fws)
{
    int tid = blockIdx.x * 256 + threadIdx.x;
    if (tid >= B2_CELLS * NB) return;
    int b = tid / B2_CELLS;
    int r = tid - b * B2_CELLS + A_CELLS;
    int lvl = B2_FIRST;
#pragma unroll
    for (int l = B2_FIRST + 1; l <= 12; ++l) lvl += (r >= c_CUM[l]);
    int P = c_P[lvl], kh = c_KH[lvl];
    int cell = r - c_CUM[lvl];
    int iy = cell / P, ix = cell - iy * P;

    const float* p = img + (size_t)b * 196608 + (size_t)(iy * kh) * 256 + ix * kh;
    float m0 = -INFINITY, m1 = -INFINITY, m2 = -INFINITY;
    for (int rr = 0; rr < kh; ++rr)
        for (int cc = 0; cc < kh; ++cc) {
            int o = rr * 256 + cc;
            m0 = fmaxf(m0, p[o]);
            m1 = fmaxf(m1, p[65536 + o]);
            m2 = fmaxf(m2, p[131072 + o]);
        }
    uint32_t gg = hash3(m0, m1, m2, c_G[lvl]);
    const float* T = tab + (size_t)lvl * 196608 + gg * 3;
    float* f = fws + ((size_t)c_CUM[lvl] * NB + (size_t)b * (P * P) + cell) * 3;
    f[0] = T[0]; f[1] = T[1]; f[2] = T[2];
}

// ---- Phase 1c: levels 13..15 (kh=1, P=256): identity bilinear -> direct ----
__global__ __launch_bounds__(256) void pool_direct(const float* __restrict__ img,
                                                   const float* __restrict__ tab,
                                                   float* __restrict__ out)
{
    int b   = blockIdx.x >> 8;
    int pix = ((blockIdx.x & 255) << 8) + threadIdx.x;
    const float* p = img + (size_t)b * 196608 + pix;
    float i0 = p[0], i1 = p[65536], i2 = p[131072];
#pragma unroll
    for (int lvl = 13; lvl < 16; ++lvl) {
        uint32_t gg = hash3(i0, i1, i2, c_G[lvl]);
        const float* T = tab + (size_t)lvl * 196608 + gg * 3;
        float* o = out + ((size_t)b * 48 + 3 * lvl) * 65536 + pix;
        o[0]      = T[0];
        o[65536]  = T[1];
        o[131072] = T[2];
    }
}

// ---- Phase 2: levels 0..12, bilinear upsample from dense f_ws via LDS ----
// src = ((2o+1)*P - 256)/512 : exact int; frac exact in fp32.
__global__ __launch_bounds__(256) void upsample(const float* __restrict__ fws,
                                                float* __restrict__ out)
{
    __shared__ float s0[384], s1[384];
    int y     = blockIdx.x;
    int plane = blockIdx.y;          // lvl*16 + b, lvl in [0,13)
    int lvl   = plane >> 4;
    int b     = plane & 15;
    int P     = c_P[lvl];

    int numy = (2 * y + 1) * P - 256;
    int iy0  = numy >> 9;
    float fy = (float)(numy & 511) * (1.0f / 512.0f);
    int iy1;
    if (iy0 < 0)            { iy0 = 0;     iy1 = 0;     fy = 0.f; }
    else if (iy0 >= P - 1)  { iy0 = P - 1; iy1 = P - 1; fy = 0.f; }
    else                    { iy1 = iy0 + 1; }

    const float* fb = fws + ((size_t)c_CUM[lvl] * NB + (size_t)b * P * P) * 3;
    const float* f0 = fb + (size_t)iy0 * P * 3;
    const float* f1 = fb + (size_t)iy1 * P * 3;
    int rowsz = P * 3;
    for (int j = threadIdx.x; j < rowsz; j += 256) {
        s0[j] = f0[j];
        s1[j] = f1[j];
    }
    __syncthreads();

    int x = threadIdx.x;
    int numx = (2 * x + 1) * P - 256;
    int ix0  = numx >> 9;
    float fx = (float)(numx & 511) * (1.0f / 512.0f);
    int ix1;
    if (ix0 < 0)            { ix0 = 0;     ix1 = 0;     fx = 0.f; }
    else if (ix0 >= P - 1)  { ix0 = P - 1; ix1 = P - 1; fx = 0.f; }
    else                    { ix1 = ix0 + 1; }

    float wx0 = 1.f - fx, wx1 = fx, wy0 = 1.f - fy, wy1 = fy;
    float* o = out + ((size_t)b * 48 + 3 * lvl) * 65536 + (size_t)y * 256 + x;
#pragma unroll
    for (int c = 0; c < 3; ++c) {
        float t00 = s0[ix0 * 3 + c], t01 = s0[ix1 * 3 + c];
        float t10 = s1[ix0 * 3 + c], t11 = s1[ix1 * 3 + c];
        float v = wy0 * (wx0 * t00 + wx1 * t01) + wy1 * (wx0 * t10 + wx1 * t11);
        o[(size_t)c * 65536] = v;
    }
}

extern "C" void kernel_launch(void* const* d_in, const int* in_sizes, int n_in,
                              void* d_out, int out_size, void* d_ws, size_t ws_size,
                              hipStream_t stream)
{
    const float* img = (const float*)d_in[0];   // (16,3,256,256) f32
    const float* tab = (const float*)d_in[1];   // (16,65536,3) f32
    float* out = (float*)d_out;                 // (16,48,256,256) f32
    float* fws = (float*)d_ws;                  // 33354*16*3 f32 = 6.4 MB

    hipLaunchKernelGGL(pool_wave,   dim3((A_CELLS * NB) / 4), dim3(256), 0, stream, img, tab, fws);
    hipLaunchKernelGGL(pool_thread, dim3((B2_CELLS * NB + 255) / 256), dim3(256), 0, stream, img, tab, fws);
    hipLaunchKernelGGL(pool_direct, dim3(NB * 256), dim3(256), 0, stream, img, tab, out);
    hipLaunchKernelGGL(upsample,    dim3(256, 13 * 16), dim3(256), 0, stream, fws, out);
}

// Round 4
// 106.201 us; speedup vs baseline: 1.6185x; 1.1891x over previous
//
#include <hip/hip_runtime.h>
#include <stdint.h>
#include <math.h>

// Multiresolution hash encoding, 16 levels.
// grids = {4,5,6,9,12,15,21,27,36,48,63,84,111,147,194,255}
// kh = 256//grid, P = floor(256/kh).
// Levels 13..15: kh=1, P=256 -> bilinear identity -> direct gather kernel.
// Levels 0..12: fused pool kernel gathers T[g] per cell into dense fws
// (float3/cell); upsample4 does bilinear from LDS-staged rows, 4 rows/block,
// 4 px/thread, float4 stores.

#define NLVL 16
#define NB   16

__constant__ int   c_P[NLVL]   = {4,5,6,9,12,15,21,28,36,51,64,85,128,256,256,256};
__constant__ int   c_KH[NLVL]  = {64,51,42,28,21,17,12,9,7,5,4,3,2,1,1,1};
__constant__ float c_G[NLVL]   = {4.f,5.f,6.f,9.f,12.f,15.f,21.f,27.f,36.f,48.f,63.f,84.f,111.f,147.f,194.f,255.f};
// prefix sums of P^2 for levels 0..12 (cells per batch), total 33354
__constant__ int   c_CUM[14]   = {0,16,41,77,158,302,527,968,1752,3048,5649,9745,16970,33354};

#define A_LVLS    9        // levels 0..8: wave-per-cell
#define A_CELLS   3048     // cells/batch, levels 0..8
#define A_BLOCKS  12192    // A_CELLS*16/4 waves-per-block
#define B2_FIRST  9        // levels 9..12: thread-per-cell
#define B2_CELLS  30306    // 33354 - 3048
#define B2_THREADS (B2_CELLS*NB)          // 484896
#define B2_BLOCKS ((B2_THREADS + 255)/256) // 1895

__device__ __forceinline__ uint32_t hash3(float m0, float m1, float m2, float g) {
    uint32_t v0 = (uint32_t)(int)(m0 * g);
    uint32_t v1 = (uint32_t)(int)(m1 * g);
    uint32_t v2 = (uint32_t)(int)(m2 * g);
    return (v0 ^ (v1 * 2654435761u) ^ (v2 * 805459861u)) & 0xFFFFu;
}

// ---- Phase 1: levels 0..12 pooling + table gather into dense fws ----
__global__ __launch_bounds__(256) void pool_all(const float* __restrict__ img,
                                                const float* __restrict__ tab,
                                                float* __restrict__ fws)
{
    if (blockIdx.x < A_BLOCKS) {
        // wave path, levels 0..8: 2D lane map (col = lane%kh, row-group = lane/kh)
        int wid  = blockIdx.x * 4 + (threadIdx.x >> 6);
        int lane = threadIdx.x & 63;
        int b = wid / A_CELLS;
        int r = wid - b * A_CELLS;
        int lvl = 0;
#pragma unroll
        for (int l = 1; l < A_LVLS; ++l) lvl += (r >= c_CUM[l]);
        int P = c_P[lvl], kh = c_KH[lvl];
        int cell = r - c_CUM[lvl];
        int iy = cell / P, ix = cell - iy * P;

        int G   = 64 / kh;          // row-groups
        int col = lane % kh;
        int grp = lane / kh;

        float m0 = -INFINITY, m1 = -INFINITY, m2 = -INFINITY;
        if (grp < G) {
            const float* p = img + (size_t)b * 196608 + (size_t)(iy * kh) * 256 + ix * kh + col;
            for (int rr = grp; rr < kh; rr += G) {
                int o = rr * 256;
                m0 = fmaxf(m0, p[o]);
                m1 = fmaxf(m1, p[65536 + o]);
                m2 = fmaxf(m2, p[131072 + o]);
            }
        }
#pragma unroll
        for (int off = 32; off > 0; off >>= 1) {
            m0 = fmaxf(m0, __shfl_xor(m0, off, 64));
            m1 = fmaxf(m1, __shfl_xor(m1, off, 64));
            m2 = fmaxf(m2, __shfl_xor(m2, off, 64));
        }
        if (lane == 0) {
            uint32_t gg = hash3(m0, m1, m2, c_G[lvl]);
            const float* T = tab + (size_t)lvl * 196608 + gg * 3;
            float* f = fws + ((size_t)c_CUM[lvl] * NB + (size_t)b * (P * P) + cell) * 3;
            f[0] = T[0]; f[1] = T[1]; f[2] = T[2];
        }
    } else {
        // thread path, levels 9..12 (kh <= 5)
        int tid = (blockIdx.x - A_BLOCKS) * 256 + threadIdx.x;
        if (tid >= B2_THREADS) return;
        int b = tid / B2_CELLS;
        int r = tid - b * B2_CELLS + A_CELLS;
        int lvl = B2_FIRST;
#pragma unroll
        for (int l = B2_FIRST + 1; l <= 12; ++l) lvl += (r >= c_CUM[l]);
        int P = c_P[lvl], kh = c_KH[lvl];
        int cell = r - c_CUM[lvl];
        int iy = cell / P, ix = cell - iy * P;

        const float* p = img + (size_t)b * 196608 + (size_t)(iy * kh) * 256 + ix * kh;
        float m0 = -INFINITY, m1 = -INFINITY, m2 = -INFINITY;
        for (int rr = 0; rr < kh; ++rr)
            for (int cc = 0; cc < kh; ++cc) {
                int o = rr * 256 + cc;
                m0 = fmaxf(m0, p[o]);
                m1 = fmaxf(m1, p[65536 + o]);
                m2 = fmaxf(m2, p[131072 + o]);
            }
        uint32_t gg = hash3(m0, m1, m2, c_G[lvl]);
        const float* T = tab + (size_t)lvl * 196608 + gg * 3;
        float* f = fws + ((size_t)c_CUM[lvl] * NB + (size_t)b * (P * P) + cell) * 3;
        f[0] = T[0]; f[1] = T[1]; f[2] = T[2];
    }
}

// ---- Phase 1c: levels 13..15 direct (identity bilinear), 4 px/thread ----
__global__ __launch_bounds__(256) void pool_direct4(const float* __restrict__ img,
                                                    const float* __restrict__ tab,
                                                    float* __restrict__ out)
{
    int t = blockIdx.x * 256 + threadIdx.x;     // 262144 total
    int b = t >> 14;                            // 16384 quads per batch
    int pix0 = (t & 16383) << 2;
    const float* p = img + (size_t)b * 196608 + pix0;
    float4 i0 = *(const float4*)p;
    float4 i1 = *(const float4*)(p + 65536);
    float4 i2 = *(const float4*)(p + 131072);
#pragma unroll
    for (int lvl = 13; lvl < 16; ++lvl) {
        float g = c_G[lvl];
        const float* T = tab + (size_t)lvl * 196608;
        uint32_t g0 = hash3(i0.x, i1.x, i2.x, g);
        uint32_t g1 = hash3(i0.y, i1.y, i2.y, g);
        uint32_t g2 = hash3(i0.z, i1.z, i2.z, g);
        uint32_t g3 = hash3(i0.w, i1.w, i2.w, g);
        float4 o0, o1, o2;
        o0.x = T[g0*3];   o1.x = T[g0*3+1]; o2.x = T[g0*3+2];
        o0.y = T[g1*3];   o1.y = T[g1*3+1]; o2.y = T[g1*3+2];
        o0.z = T[g2*3];   o1.z = T[g2*3+1]; o2.z = T[g2*3+2];
        o0.w = T[g3*3];   o1.w = T[g3*3+1]; o2.w = T[g3*3+2];
        float* ob = out + ((size_t)b * 48 + 3 * lvl) * 65536 + pix0;
        *(float4*)ob            = o0;
        *(float4*)(ob + 65536)  = o1;
        *(float4*)(ob + 131072) = o2;
    }
}

// ---- Phase 2: levels 0..12 bilinear upsample, 4 rows/block, 4 px/thread ----
// src = ((2o+1)*P - 256)/512 : exact int; frac exact in fp32.
__global__ __launch_bounds__(256) void upsample4(const float* __restrict__ fws,
                                                 float* __restrict__ out)
{
    __shared__ float s[1536];        // up to 4 rows x 128*3 floats
    int plane = blockIdx.y;          // lvl*16 + b, lvl in [0,13)
    int lvl   = plane >> 4;
    int b     = plane & 15;
    int P     = c_P[lvl];
    int rowsz = P * 3;
    int y0    = blockIdx.x * 4;

    // staged source-row range for ys y0..y0+3 (cnt <= 4, proven)
    int i0f = ((2 * y0 + 1) * P - 256) >> 9;
    int r0  = i0f < 0 ? 0 : (i0f > P - 1 ? P - 1 : i0f);
    int i0l = ((2 * (y0 + 3) + 1) * P - 256) >> 9;
    int i1l = i0l < 0 ? 0 : (i0l + 1 > P - 1 ? P - 1 : i0l + 1);
    int cnt = i1l - r0 + 1;

    const float* fb = fws + ((size_t)c_CUM[lvl] * NB + (size_t)b * P * P + (size_t)r0 * P) * 3;
    for (int j = threadIdx.x; j < cnt * rowsz; j += 256) s[j] = fb[j];
    __syncthreads();

    int w    = threadIdx.x >> 6;
    int lane = threadIdx.x & 63;
    int y    = y0 + w;

    int numy = (2 * y + 1) * P - 256;
    int iy0  = numy >> 9;
    float fy = (float)(numy & 511) * (1.0f / 512.0f);
    int iy1;
    if (iy0 < 0)           { iy0 = 0;     iy1 = 0;     fy = 0.f; }
    else if (iy0 >= P - 1) { iy0 = P - 1; iy1 = P - 1; fy = 0.f; }
    else                   { iy1 = iy0 + 1; }
    const float* s0 = s + (iy0 - r0) * rowsz;
    const float* s1 = s + (iy1 - r0) * rowsz;
    float wy0 = 1.f - fy, wy1 = fy;

    float v[3][4];
    int xb = lane << 2;
#pragma unroll
    for (int j = 0; j < 4; ++j) {
        int numx = (2 * (xb + j) + 1) * P - 256;
        int ix0  = numx >> 9;
        float fx = (float)(numx & 511) * (1.0f / 512.0f);
        int ix1;
        if (ix0 < 0)           { ix0 = 0;     ix1 = 0;     fx = 0.f; }
        else if (ix0 >= P - 1) { ix0 = P - 1; ix1 = P - 1; fx = 0.f; }
        else                   { ix1 = ix0 + 1; }
        float wx0 = 1.f - fx, wx1 = fx;
#pragma unroll
        for (int c = 0; c < 3; ++c) {
            float t00 = s0[ix0 * 3 + c], t01 = s0[ix1 * 3 + c];
            float t10 = s1[ix0 * 3 + c], t11 = s1[ix1 * 3 + c];
            v[c][j] = wy0 * (wx0 * t00 + wx1 * t01) + wy1 * (wx0 * t10 + wx1 * t11);
        }
    }
    float* o = out + ((size_t)b * 48 + 3 * lvl) * 65536 + (size_t)y * 256 + xb;
#pragma unroll
    for (int c = 0; c < 3; ++c) {
        float4 q; q.x = v[c][0]; q.y = v[c][1]; q.z = v[c][2]; q.w = v[c][3];
        *(float4*)(o + (size_t)c * 65536) = q;
    }
}

extern "C" void kernel_launch(void* const* d_in, const int* in_sizes, int n_in,
                              void* d_out, int out_size, void* d_ws, size_t ws_size,
                              hipStream_t stream)
{
    const float* img = (const float*)d_in[0];   // (16,3,256,256) f32
    const float* tab = (const float*)d_in[1];   // (16,65536,3) f32
    float* out = (float*)d_out;                 // (16,48,256,256) f32
    float* fws = (float*)d_ws;                  // 33354*16*3 f32 = 6.4 MB

    hipLaunchKernelGGL(pool_all,     dim3(A_BLOCKS + B2_BLOCKS), dim3(256), 0, stream, img, tab, fws);
    hipLaunchKernelGGL(pool_direct4, dim3(1024), dim3(256), 0, stream, img, tab, out);
    hipLaunchKernelGGL(upsample4,    dim3(64, 13 * 16), dim3(256), 0, stream, fws, out);
}